// Round 1
// baseline (475.363 us; speedup 1.0000x reference)
//
#include <hip/hip_runtime.h>
#include <hip/hip_cooperative_groups.h>

namespace cg = cooperative_groups;

#define DDIM  2048
#define KC    8
#define CH1   32          // stage-1 reduction chunks
#define TBA   4           // tokens per batch, phase A
#define TBF   4           // tokens per batch, phase C
#define GRID  512         // 2 blocks/CU * 256 CUs -> co-resident with launch_bounds(256,2)

typedef float nfloat4 __attribute__((ext_vector_type(4)));
typedef unsigned short ushortv8 __attribute__((ext_vector_type(8)));
typedef unsigned short ushortv4 __attribute__((ext_vector_type(4)));

__device__ __forceinline__ void nt_store4(const float4& v, float* p){
  nfloat4 nv; nv.x = v.x; nv.y = v.y; nv.z = v.z; nv.w = v.w;
  __builtin_nontemporal_store(nv, (nfloat4*)p);
}

// bf16 round-to-nearest-even pack/unpack
__device__ __forceinline__ unsigned short f2bf(float f){
  unsigned u = __float_as_uint(f);
  u += 0x7fffu + ((u >> 16) & 1u);
  return (unsigned short)(u >> 16);
}
__device__ __forceinline__ float bf2f(unsigned short h){
  return __uint_as_float(((unsigned)h) << 16);
}

__device__ __forceinline__ float wave_sum(float v){
  #pragma unroll
  for (int off = 32; off > 0; off >>= 1)
    v += __shfl_xor(v, off, 64);
  return v;
}

// Multi-value butterfly: sum v[0..7] across 64 lanes in 10 shuffles.
// On exit, lane l (l<8) holds the full wave-sum for k = 4*(l&1)+2*((l>>1)&1)+((l>>2)&1).
__device__ __forceinline__ float butterfly8(float v[8], int t){
  {
    const bool h = (t & 1);
    #pragma unroll
    for (int j = 0; j < 4; ++j){
      float s    = h ? v[j]   : v[j+4];
      float keep = h ? v[j+4] : v[j];
      v[j] = keep + __shfl_xor(s, 1, 64);
    }
  }
  {
    const bool h = (t & 2);
    #pragma unroll
    for (int j = 0; j < 2; ++j){
      float s    = h ? v[j]   : v[j+2];
      float keep = h ? v[j+2] : v[j];
      v[j] = keep + __shfl_xor(s, 2, 64);
    }
  }
  {
    const bool h = (t & 4);
    float s    = h ? v[0] : v[1];
    float keep = h ? v[1] : v[0];
    v[0] = keep + __shfl_xor(s, 4, 64);
  }
  v[0] += __shfl_xor(v[0], 8, 64);
  v[0] += __shfl_xor(v[0], 16, 64);
  v[0] += __shfl_xor(v[0], 32, 64);
  return v[0];
}

__device__ __forceinline__ float gelu_tanh(float v){
  const float c = 0.7978845608028654f;
  float tt = c * v * (1.0f + 0.044715f * v * v);
  float e  = __expf(2.0f * tt);
  float th = 1.0f - 2.0f / (e + 1.0f);
  return 0.5f * v * (1.0f + th);
}

// ---------------------------------------------------------------------------
// Phase A: per-token argmax assignment + per-block segment partial sums.
// psums written as bf16 (RNE); momentum 0.999 crushes the quantization error.
// Scalar-branch accumulate via readfirstlane (assignment is block-uniform).
// ---------------------------------------------------------------------------
__device__ __forceinline__ void phase_assign(const float* __restrict__ x,
    const float* __restrict__ proto, unsigned short* __restrict__ psums,
    float* __restrict__ pcnts, int ntok, int bid, int gsz)
{
  const int t = threadIdx.x;
  const int wave = t >> 6, lane = t & 63;
  const int d0 = 4*t, d1 = DDIM/2 + 4*t;
  const int kidx = ((lane&1)<<2) | (lane&2) | ((lane>>2)&1);

  __shared__ float rednorm[4*KC];
  __shared__ float redA[TBA][4][KC];
  __shared__ float sInvA[KC];
  __shared__ float sCnt[KC];
  __shared__ int   sAsg[TBA];

  float4 P0[KC], P1[KC], acc0[KC], acc1[KC];
  #pragma unroll
  for (int k = 0; k < KC; ++k){
    P0[k] = *(const float4*)(proto + k*DDIM + d0);
    P1[k] = *(const float4*)(proto + k*DDIM + d1);
    acc0[k] = make_float4(0.f,0.f,0.f,0.f);
    acc1[k] = make_float4(0.f,0.f,0.f,0.f);
  }
  if (t < KC) sCnt[t] = 0.f;

  // 1/||P_k|| (eps 1e-12). argmax of dot*invP == argmax of clipped cosine.
  #pragma unroll
  for (int k = 0; k < KC; ++k){
    float ss = P0[k].x*P0[k].x + P0[k].y*P0[k].y + P0[k].z*P0[k].z + P0[k].w*P0[k].w
             + P1[k].x*P1[k].x + P1[k].y*P1[k].y + P1[k].z*P1[k].z + P1[k].w*P1[k].w;
    ss = wave_sum(ss);
    if (lane == 0) rednorm[wave*KC + k] = ss;
  }
  __syncthreads();
  if (t < KC){
    float ss = rednorm[t] + rednorm[KC + t] + rednorm[2*KC + t] + rednorm[3*KC + t];
    sInvA[t] = 1.0f / fmaxf(sqrtf(ss), 1e-12f);
  }
  __syncthreads();

  const int stride = gsz * TBA;
  float4 X0[TBA], X1[TBA], N0[TBA], N1[TBA];
  int tok0 = bid * TBA;
  #pragma unroll
  for (int i = 0; i < TBA; ++i){
    int tk = tok0 + i;
    X0[i] = make_float4(0,0,0,0); X1[i] = make_float4(0,0,0,0);
    if (tk < ntok){
      X0[i] = *(const float4*)(x + (size_t)tk*DDIM + d0);
      X1[i] = *(const float4*)(x + (size_t)tk*DDIM + d1);
    }
  }

  for (; tok0 < ntok; tok0 += stride){
    const int ntok0 = tok0 + stride;
    #pragma unroll
    for (int i = 0; i < TBA; ++i){
      int tk = ntok0 + i;
      N0[i] = make_float4(0,0,0,0); N1[i] = make_float4(0,0,0,0);
      if (tk < ntok){
        N0[i] = *(const float4*)(x + (size_t)tk*DDIM + d0);
        N1[i] = *(const float4*)(x + (size_t)tk*DDIM + d1);
      }
    }
    #pragma unroll
    for (int i = 0; i < TBA; ++i){
      float v[KC];
      #pragma unroll
      for (int k = 0; k < KC; ++k){
        v[k] = X0[i].x*P0[k].x + X0[i].y*P0[k].y + X0[i].z*P0[k].z + X0[i].w*P0[k].w
             + X1[i].x*P1[k].x + X1[i].y*P1[k].y + X1[i].z*P1[k].z + X1[i].w*P1[k].w;
      }
      float r = butterfly8(v, t);
      if (lane < 8) redA[i][wave][kidx] = r;
    }
    __syncthreads();
    if (t < TBA && tok0 + t < ntok){
      int best = 0; float bv = -3.4e38f;
      #pragma unroll
      for (int k = 0; k < KC; ++k){
        float val = (redA[t][0][k] + redA[t][1][k] + redA[t][2][k] + redA[t][3][k]) * sInvA[k];
        if (val > bv){ bv = val; best = k; }   // strict > : first index wins ties
      }
      sAsg[t] = best;
      atomicAdd(&sCnt[best], 1.0f);
    }
    __syncthreads();
    #pragma unroll
    for (int i = 0; i < TBA; ++i){
      if (tok0 + i < ntok){
        // block-uniform assignment -> force SGPR -> scalar branch, 1/8 bodies exec
        const int a = __builtin_amdgcn_readfirstlane(sAsg[i]);
        #pragma unroll
        for (int k = 0; k < KC; ++k){
          if (a == k){
            acc0[k].x += X0[i].x; acc0[k].y += X0[i].y; acc0[k].z += X0[i].z; acc0[k].w += X0[i].w;
            acc1[k].x += X1[i].x; acc1[k].y += X1[i].y; acc1[k].z += X1[i].z; acc1[k].w += X1[i].w;
          }
        }
      }
    }
    #pragma unroll
    for (int i = 0; i < TBA; ++i){ X0[i] = N0[i]; X1[i] = N1[i]; }
  }
  __syncthreads();

  // psums layout (bf16, thread-major permuted): [b][k][t*8 + j],
  // j<4 -> natural dim 4t+j ; j>=4 -> natural dim 1024+4t+(j-4).
  unsigned short* dst = psums + (size_t)bid * (KC*DDIM);
  #pragma unroll
  for (int k = 0; k < KC; ++k){
    ushortv8 o;
    o[0] = f2bf(acc0[k].x); o[1] = f2bf(acc0[k].y); o[2] = f2bf(acc0[k].z); o[3] = f2bf(acc0[k].w);
    o[4] = f2bf(acc1[k].x); o[5] = f2bf(acc1[k].y); o[6] = f2bf(acc1[k].z); o[7] = f2bf(acc1[k].w);
    *(ushortv8*)(dst + k*DDIM + t*8) = o;
  }
  if (t < KC) pcnts[bid*KC + t] = sCnt[t];
}

// ---------------------------------------------------------------------------
// Phase R1: nb bf16 partials -> CH1 fp32 chunk-partials (positions passthrough).
// ---------------------------------------------------------------------------
__device__ __forceinline__ void phase_reduce1(const unsigned short* __restrict__ psums,
    const float* __restrict__ pcnts, float* __restrict__ stage2, float* __restrict__ cnt2,
    int nb, int bid, int gsz)
{
  const int cs = (nb + CH1 - 1) / CH1;
  for (int job = bid; job < CH1*16; job += gsz){
    const int ch = job >> 4;            // 0..CH1-1
    const int gq = job & 15;            // 0..15
    const int col = gq*1024 + threadIdx.x*4;   // element column (bf16 units), 4-wide
    const int b0 = ch*cs;
    float4 acc = make_float4(0.f,0.f,0.f,0.f);
    #pragma unroll 4
    for (int i = 0; i < cs; ++i){
      int b = b0 + i;
      if (b < nb){
        ushortv4 v = *(const ushortv4*)(psums + (size_t)b*(KC*DDIM) + col);
        acc.x += bf2f(v[0]); acc.y += bf2f(v[1]); acc.z += bf2f(v[2]); acc.w += bf2f(v[3]);
      }
    }
    *(float4*)(stage2 + (size_t)ch*(KC*DDIM) + col) = acc;

    if (gq == 0 && threadIdx.x < KC){
      float c = 0.f;
      for (int i = 0; i < cs; ++i){
        int b = b0 + i;
        if (b < nb) c += pcnts[b*KC + threadIdx.x];
      }
      cnt2[ch*KC + threadIdx.x] = c;
    }
  }
}

// ---------------------------------------------------------------------------
// Phase mid (fused reduce2 + pupdate): block k (k<8) sums CH1 chunk-partials of
// cluster k, builds centroid (count>0 fallback proto), normalizes, applies
// momentum, renormalizes, writes p2n in the same thread-major permuted layout.
// ---------------------------------------------------------------------------
__device__ __forceinline__ void phase_mid(const float* __restrict__ stage2,
    const float* __restrict__ cnt2, const float* __restrict__ proto,
    float* __restrict__ p2n, int bid)
{
  __shared__ float sR1[4], sR2[4];
  if (bid < KC){
    const int k = bid, t = threadIdx.x;
    const int wave = t >> 6, lane = t & 63;

    float c = 0.f;
    #pragma unroll
    for (int ch = 0; ch < CH1; ++ch) c += cnt2[ch*KC + k];

    float4 s0 = make_float4(0.f,0.f,0.f,0.f), s1 = make_float4(0.f,0.f,0.f,0.f);
    #pragma unroll
    for (int ch = 0; ch < CH1; ++ch){
      const float* p = stage2 + (size_t)ch*(KC*DDIM) + k*DDIM + t*8;
      float4 a = *(const float4*)p;
      float4 b = *(const float4*)(p + 4);
      s0.x += a.x; s0.y += a.y; s0.z += a.z; s0.w += a.w;
      s1.x += b.x; s1.y += b.y; s1.z += b.z; s1.w += b.w;
    }
    // natural-layout proto loads matching the permuted positions
    float4 pr0 = *(const float4*)(proto + k*DDIM + 4*t);
    float4 pr1 = *(const float4*)(proto + k*DDIM + DDIM/2 + 4*t);

    float4 c0, c1;
    if (c > 0.f){
      float inv = 1.0f / fmaxf(c, 1.f);
      c0.x = s0.x*inv; c0.y = s0.y*inv; c0.z = s0.z*inv; c0.w = s0.w*inv;
      c1.x = s1.x*inv; c1.y = s1.y*inv; c1.z = s1.z*inv; c1.w = s1.w*inv;
    } else { c0 = pr0; c1 = pr1; }

    float ss = c0.x*c0.x + c0.y*c0.y + c0.z*c0.z + c0.w*c0.w
             + c1.x*c1.x + c1.y*c1.y + c1.z*c1.z + c1.w*c1.w;
    ss = wave_sum(ss);
    if (lane == 0) sR1[wave] = ss;
    __syncthreads();
    ss = sR1[0] + sR1[1] + sR1[2] + sR1[3];
    const float invc = 1.0f / fmaxf(sqrtf(ss), 1e-12f);

    const float m = 0.999f, om = 1.0f - 0.999f;
    float4 p20, p21;
    p20.x = m*pr0.x + om*c0.x*invc; p20.y = m*pr0.y + om*c0.y*invc;
    p20.z = m*pr0.z + om*c0.z*invc; p20.w = m*pr0.w + om*c0.w*invc;
    p21.x = m*pr1.x + om*c1.x*invc; p21.y = m*pr1.y + om*c1.y*invc;
    p21.z = m*pr1.z + om*c1.z*invc; p21.w = m*pr1.w + om*c1.w*invc;

    float ss2 = p20.x*p20.x + p20.y*p20.y + p20.z*p20.z + p20.w*p20.w
              + p21.x*p21.x + p21.y*p21.y + p21.z*p21.z + p21.w*p21.w;
    ss2 = wave_sum(ss2);
    if (lane == 0) sR2[wave] = ss2;
    __syncthreads();
    ss2 = sR2[0] + sR2[1] + sR2[2] + sR2[3];
    const float inv2 = 1.0f / fmaxf(sqrtf(ss2), 1e-8f);

    float4 o0, o1;
    o0.x = p20.x*inv2; o0.y = p20.y*inv2; o0.z = p20.z*inv2; o0.w = p20.w*inv2;
    o1.x = p21.x*inv2; o1.y = p21.y*inv2; o1.z = p21.z*inv2; o1.w = p21.w*inv2;
    *(float4*)(p2n + k*DDIM + t*8)     = o0;   // permuted: thread t owns elems t*8..t*8+7
    *(float4*)(p2n + k*DDIM + t*8 + 4) = o1;
  }
}

// ---------------------------------------------------------------------------
// Phase C: sims2 -> novelty -> scale -> gelu(x*scale).
// p2n is permuted -> each thread's prototype slice is one contiguous 32 B read.
// ---------------------------------------------------------------------------
__device__ __forceinline__ void phase_final(const float* __restrict__ x,
    const float* __restrict__ p2n, const float* __restrict__ plt,
    const float* __restrict__ plb, float* __restrict__ out, int ntok, int bid, int gsz)
{
  const int t = threadIdx.x;
  const int wave = t >> 6, lane = t & 63;
  const int d0 = 4*t, d1 = DDIM/2 + 4*t;
  const int kidx = ((lane&1)<<2) | (lane&2) | ((lane>>2)&1);

  __shared__ float redF[TBF][4][KC];
  __shared__ float redss[TBF][4];
  __shared__ float sScale[TBF];

  float4 P0[KC], P1[KC];
  #pragma unroll
  for (int k = 0; k < KC; ++k){
    P0[k] = *(const float4*)(p2n + k*DDIM + t*8);
    P1[k] = *(const float4*)(p2n + k*DDIM + t*8 + 4);
  }
  const float tau   = __expf(plt[0]);
  const float alpha = 1.0f / (1.0f + __expf(-plb[0]));

  const int stride = gsz * TBF;
  float4 X0[TBF], X1[TBF], N0[TBF], N1[TBF];
  int tok0 = bid * TBF;
  #pragma unroll
  for (int i = 0; i < TBF; ++i){
    int tk = tok0 + i;
    X0[i] = make_float4(0,0,0,0); X1[i] = make_float4(0,0,0,0);
    if (tk < ntok){
      X0[i] = *(const float4*)(x + (size_t)tk*DDIM + d0);
      X1[i] = *(const float4*)(x + (size_t)tk*DDIM + d1);
    }
  }

  for (; tok0 < ntok; tok0 += stride){
    const int ntok0 = tok0 + stride;
    #pragma unroll
    for (int i = 0; i < TBF; ++i){
      int tk = ntok0 + i;
      N0[i] = make_float4(0,0,0,0); N1[i] = make_float4(0,0,0,0);
      if (tk < ntok){
        N0[i] = *(const float4*)(x + (size_t)tk*DDIM + d0);
        N1[i] = *(const float4*)(x + (size_t)tk*DDIM + d1);
      }
    }
    #pragma unroll
    for (int i = 0; i < TBF; ++i){
      float v[KC];
      #pragma unroll
      for (int k = 0; k < KC; ++k){
        v[k] = X0[i].x*P0[k].x + X0[i].y*P0[k].y + X0[i].z*P0[k].z + X0[i].w*P0[k].w
             + X1[i].x*P1[k].x + X1[i].y*P1[k].y + X1[i].z*P1[k].z + X1[i].w*P1[k].w;
      }
      float r = butterfly8(v, t);
      if (lane < 8) redF[i][wave][kidx] = r;
      float ss = X0[i].x*X0[i].x + X0[i].y*X0[i].y + X0[i].z*X0[i].z + X0[i].w*X0[i].w
               + X1[i].x*X1[i].x + X1[i].y*X1[i].y + X1[i].z*X1[i].z + X1[i].w*X1[i].w;
      ss = wave_sum(ss);
      if (lane == 0) redss[i][wave] = ss;
    }
    __syncthreads();
    if (t < TBF && tok0 + t < ntok){
      float fss = redss[t][0] + redss[t][1] + redss[t][2] + redss[t][3];
      float inv = 1.0f / fmaxf(sqrtf(fss), 1e-8f);   // xn eps 1e-8
      float mx = -3.4e38f;
      #pragma unroll
      for (int k = 0; k < KC; ++k){
        float val = redF[t][0][k] + redF[t][1][k] + redF[t][2][k] + redF[t][3][k];
        mx = fmaxf(mx, val);
      }
      float s    = fminf(fmaxf(mx * inv, -1.0f), 1.0f);   // clip(max) == max(clip)
      float dist = fminf(fmaxf(1.0f - s, 0.0f), 2.0f);
      float nov  = 1.0f - __expf(-tau * dist);
      float sc   = 1.0f - alpha + alpha * nov;
      sScale[t]  = fminf(fmaxf(sc, 0.1f), 10.0f);
    }
    __syncthreads();
    #pragma unroll
    for (int i = 0; i < TBF; ++i){
      int tk = tok0 + i;
      if (tk < ntok){
        const float sc = sScale[i];
        float* o = out + (size_t)tk*DDIM;
        float4 o0, o1;
        o0.x = gelu_tanh(X0[i].x*sc); o0.y = gelu_tanh(X0[i].y*sc);
        o0.z = gelu_tanh(X0[i].z*sc); o0.w = gelu_tanh(X0[i].w*sc);
        o1.x = gelu_tanh(X1[i].x*sc); o1.y = gelu_tanh(X1[i].y*sc);
        o1.z = gelu_tanh(X1[i].z*sc); o1.w = gelu_tanh(X1[i].w*sc);
        nt_store4(o0, o + d0);
        nt_store4(o1, o + d1);
      }
    }
    #pragma unroll
    for (int i = 0; i < TBF; ++i){ X0[i] = N0[i]; X1[i] = N1[i]; }
  }
}

// ---------------------------------------------------------------------------
// Fused cooperative kernel: A -> sync -> R1 -> sync -> mid -> sync -> C
// ---------------------------------------------------------------------------
__global__ __launch_bounds__(256, 2)
void k_fused(const float* __restrict__ x, const float* __restrict__ proto,
             const float* __restrict__ plt, const float* __restrict__ plb,
             float* __restrict__ out, float* __restrict__ ws, int ntok)
{
  float* p2n    = ws;                           // 16384 (permuted fp32)
  float* pcnts  = ws + 16384;                   // GRID*8
  float* cnt2   = ws + 20480;                   // CH1*8
  float* stage2 = ws + 20736;                   // CH1*16384 fp32
  unsigned short* psums = (unsigned short*)(ws + 20736 + CH1*KC*DDIM);  // GRID*16384 bf16

  const int bid = blockIdx.x;
  const int gsz = gridDim.x;
  cg::grid_group grid = cg::this_grid();

  phase_assign(x, proto, psums, pcnts, ntok, bid, gsz);
  grid.sync();
  phase_reduce1(psums, pcnts, stage2, cnt2, gsz, bid, gsz);
  grid.sync();
  phase_mid(stage2, cnt2, proto, p2n, bid);
  grid.sync();
  phase_final(x, p2n, plt, plb, out, ntok, bid, gsz);
}

// ---------------------------------------------------------------------------
// Fallback wrappers (used only if cooperative launch is rejected).
// ---------------------------------------------------------------------------
__global__ __launch_bounds__(256, 2)
void k_s1(const float* __restrict__ x, const float* __restrict__ proto,
          unsigned short* __restrict__ psums, float* __restrict__ pcnts, int ntok)
{ phase_assign(x, proto, psums, pcnts, ntok, blockIdx.x, gridDim.x); }

__global__ __launch_bounds__(256)
void k_s2(const unsigned short* __restrict__ psums, const float* __restrict__ pcnts,
          float* __restrict__ stage2, float* __restrict__ cnt2, int nb)
{ phase_reduce1(psums, pcnts, stage2, cnt2, nb, blockIdx.x, gridDim.x); }

__global__ __launch_bounds__(256)
void k_s3(const float* __restrict__ stage2, const float* __restrict__ cnt2,
          const float* __restrict__ proto, float* __restrict__ p2n)
{ phase_mid(stage2, cnt2, proto, p2n, blockIdx.x); }

__global__ __launch_bounds__(256, 2)
void k_s4(const float* __restrict__ x, const float* __restrict__ p2n,
          const float* __restrict__ plt, const float* __restrict__ plb,
          float* __restrict__ out, int ntok)
{ phase_final(x, p2n, plt, plb, out, ntok, blockIdx.x, gridDim.x); }

extern "C" void kernel_launch(void* const* d_in, const int* in_sizes, int n_in,
                              void* d_out, int out_size, void* d_ws, size_t ws_size,
                              hipStream_t stream)
{
  const float* x          = (const float*)d_in[0];
  const float* proto      = (const float*)d_in[1];
  const float* log_tau    = (const float*)d_in[2];
  const float* log_blend  = (const float*)d_in[3];
  float* out = (float*)d_out;
  float* ws  = (float*)d_ws;

  const int ntok = in_sizes[0] / DDIM;   // 16384

  float* p2n    = ws;
  float* pcnts  = ws + 16384;
  float* cnt2   = ws + 20480;
  float* stage2 = ws + 20736;
  unsigned short* psums = (unsigned short*)(ws + 20736 + CH1*KC*DDIM);

  // args for cooperative launch (locals are copied at call time)
  const float* xa = x; const float* pa = proto;
  const float* lta = log_tau; const float* lba = log_blend;
  float* oa = out; float* wa = ws; int na = ntok;
  void* args[7] = { (void*)&xa, (void*)&pa, (void*)&lta, (void*)&lba,
                    (void*)&oa, (void*)&wa, (void*)&na };

  hipError_t err = hipLaunchCooperativeKernel((const void*)k_fused,
                                              dim3(GRID), dim3(256), args, 0, stream);
  if (err != hipSuccess){
    (void)hipGetLastError();   // clear sticky error, fall back to 4 launches
    k_s1<<<GRID,   256, 0, stream>>>(x, proto, psums, pcnts, ntok);
    k_s2<<<CH1*16, 256, 0, stream>>>(psums, pcnts, stage2, cnt2, GRID);
    k_s3<<<KC,     256, 0, stream>>>(stage2, cnt2, proto, p2n);
    k_s4<<<GRID,   256, 0, stream>>>(x, p2n, log_tau, log_blend, out, ntok);
  }
}

// Round 2
// 306.394 us; speedup vs baseline: 1.5515x; 1.5515x over previous
//
#include <hip/hip_runtime.h>

#define DDIM  2048
#define KC    8
#define NCH   32          // reduce chunks over partials
#define TPB_A 16          // tokens per block, k_assign (4 waves x 4 tokens)
#define TPB_C 16          // tokens per block, k_final

typedef float nfloat4 __attribute__((ext_vector_type(4)));
typedef unsigned short ushortv8 __attribute__((ext_vector_type(8)));
typedef unsigned short ushortv4 __attribute__((ext_vector_type(4)));

__device__ __forceinline__ void nt_store4(const float4& v, float* p){
  nfloat4 nv; nv.x = v.x; nv.y = v.y; nv.z = v.z; nv.w = v.w;
  __builtin_nontemporal_store(nv, (nfloat4*)p);
}

// bf16 round-to-nearest-even pack; unpack = shift/mask (exact)
__device__ __forceinline__ unsigned short f2bf(float f){
  unsigned u = __float_as_uint(f);
  u += 0x7fffu + ((u >> 16) & 1u);
  return (unsigned short)(u >> 16);
}
__device__ __forceinline__ float bf2f(unsigned short h){
  return __uint_as_float(((unsigned)h) << 16);
}
__device__ __forceinline__ float bflo(unsigned u){ return __uint_as_float(u << 16); }
__device__ __forceinline__ float bfhi(unsigned u){ return __uint_as_float(u & 0xffff0000u); }

__device__ __forceinline__ float wave_sum(float v){
  #pragma unroll
  for (int off = 32; off > 0; off >>= 1)
    v += __shfl_xor(v, off, 64);
  return v;   // broadcast: every lane holds the total
}

// Multi-value butterfly: sum v[0..7] across 64 lanes in 10 shuffles.
// On exit EVERY lane l holds the full wave-sum for cluster
// k = 4*(l&1) + 2*((l>>1)&1) + ((l>>2)&1)   (bits of l&7).
__device__ __forceinline__ float butterfly8(float v[8], int t){
  {
    const bool h = (t & 1);
    #pragma unroll
    for (int j = 0; j < 4; ++j){
      float s    = h ? v[j]   : v[j+4];
      float keep = h ? v[j+4] : v[j];
      v[j] = keep + __shfl_xor(s, 1, 64);
    }
  }
  {
    const bool h = (t & 2);
    #pragma unroll
    for (int j = 0; j < 2; ++j){
      float s    = h ? v[j]   : v[j+2];
      float keep = h ? v[j+2] : v[j];
      v[j] = keep + __shfl_xor(s, 2, 64);
    }
  }
  {
    const bool h = (t & 4);
    float s    = h ? v[0] : v[1];
    float keep = h ? v[1] : v[0];
    v[0] = keep + __shfl_xor(s, 4, 64);
  }
  v[0] += __shfl_xor(v[0], 8, 64);
  v[0] += __shfl_xor(v[0], 16, 64);
  v[0] += __shfl_xor(v[0], 32, 64);
  return v[0];
}

__device__ __forceinline__ float gelu_tanh(float v){
  const float c = 0.7978845608028654f;
  float tt = c * v * (1.0f + 0.044715f * v * v);
  float e  = __expf(2.0f * tt);
  float th = 1.0f - 2.0f / (e + 1.0f);
  return 0.5f * v * (1.0f + th);
}

// ---------------------------------------------------------------------------
// k_pre: P_norm = proto / max(||proto||, 1e-12), stored bf16.  Block = cluster.
// ---------------------------------------------------------------------------
__global__ __launch_bounds__(256)
void k_pre(const float* __restrict__ proto, unsigned short* __restrict__ pbf)
{
  const int k = blockIdx.x, t = threadIdx.x;
  const int wave = t >> 6, lane = t & 63;
  __shared__ float sred[4];
  const int d0 = 4*t, d1 = 1024 + 4*t;
  float4 a = *(const float4*)(proto + k*DDIM + d0);
  float4 b = *(const float4*)(proto + k*DDIM + d1);
  float ss = a.x*a.x + a.y*a.y + a.z*a.z + a.w*a.w
           + b.x*b.x + b.y*b.y + b.z*b.z + b.w*b.w;
  ss = wave_sum(ss);
  if (lane == 0) sred[wave] = ss;
  __syncthreads();
  ss = sred[0] + sred[1] + sred[2] + sred[3];
  const float inv = 1.0f / fmaxf(sqrtf(ss), 1e-12f);
  ushortv4 o0, o1;
  o0[0]=f2bf(a.x*inv); o0[1]=f2bf(a.y*inv); o0[2]=f2bf(a.z*inv); o0[3]=f2bf(a.w*inv);
  o1[0]=f2bf(b.x*inv); o1[1]=f2bf(b.y*inv); o1[2]=f2bf(b.z*inv); o1[3]=f2bf(b.w*inv);
  *(ushortv4*)(pbf + k*DDIM + d0) = o0;
  *(ushortv4*)(pbf + k*DDIM + d1) = o1;
}

// ---------------------------------------------------------------------------
// k_assign: stage 1 = wave-per-token argmax (P in LDS bf16, in-wave reduce,
// no barriers); stage 2 = thread-per-8-dims segment accumulate (x re-read,
// L3-hot), bf16 partials.  Exactly 2 __syncthreads per block.
// ---------------------------------------------------------------------------
__global__ __launch_bounds__(256, 4)
void k_assign(const float* __restrict__ x, const unsigned short* __restrict__ pbf,
              unsigned short* __restrict__ part, float* __restrict__ pcnts, int ntok)
{
  __shared__ unsigned short Pl[KC*DDIM];   // 32 KB bf16 normalized prototypes
  __shared__ int asg[TPB_A];

  const int t = threadIdx.x;
  const int wave = t >> 6, lane = t & 63;

  // stage P into LDS: 8 x 16B coalesced per thread
  #pragma unroll
  for (int j = 0; j < 8; ++j){
    const int e = (j*256 + t)*8;
    *(ushortv8*)(Pl + e) = *(const ushortv8*)(pbf + e);
  }
  __syncthreads();

  const int tok_base = blockIdx.x * TPB_A;

  // ---- stage 1: wave w -> tokens w*4 .. w*4+3 ----
  {
    const int tl0 = wave*4;
    float4 X[8], N[8];
    int tok = tok_base + tl0;
    if (tok < ntok){
      #pragma unroll
      for (int j = 0; j < 8; ++j)
        X[j] = *(const float4*)(x + (size_t)tok*DDIM + j*256 + 4*lane);
    }
    #pragma unroll
    for (int i = 0; i < 4; ++i){
      const int tok_i = tok_base + tl0 + i;
      const bool ldn = (i < 3) && (tok_i + 1 < ntok);
      if (ldn){
        #pragma unroll
        for (int j = 0; j < 8; ++j)
          N[j] = *(const float4*)(x + (size_t)(tok_i+1)*DDIM + j*256 + 4*lane);
      }
      if (tok_i < ntok){
        float v[KC];
        #pragma unroll
        for (int k = 0; k < KC; ++k){
          float s = 0.f;
          #pragma unroll
          for (int j = 0; j < 8; ++j){
            uint2 u = *(const uint2*)((const unsigned*)Pl + k*1024 + j*128 + 2*lane);
            s += X[j].x*bflo(u.x) + X[j].y*bfhi(u.x)
               + X[j].z*bflo(u.y) + X[j].w*bfhi(u.y);
          }
          v[k] = s;
        }
        float bv = butterfly8(v, lane);
        int   bi = ((lane&1)<<2) | (lane&2) | ((lane>>2)&1);
        #pragma unroll
        for (int off = 1; off < 8; off <<= 1){
          float ov = __shfl_xor(bv, off, 64);
          int   oi = __shfl_xor(bi, off, 64);
          if (ov > bv || (ov == bv && oi < bi)){ bv = ov; bi = oi; }  // first-index ties
        }
        if (lane == 0) asg[tl0 + i] = bi;
      }
      if (ldn){
        #pragma unroll
        for (int j = 0; j < 8; ++j) X[j] = N[j];
      }
    }
  }
  __syncthreads();

  // ---- stage 2: thread t owns dims {4t..4t+3, 1024+4t..+3} ----
  const int d0 = 4*t, d1 = 1024 + 4*t;
  float4 acc0[KC], acc1[KC];
  float cnt[KC];
  #pragma unroll
  for (int k = 0; k < KC; ++k){
    acc0[k] = make_float4(0.f,0.f,0.f,0.f);
    acc1[k] = make_float4(0.f,0.f,0.f,0.f);
    cnt[k] = 0.f;
  }
  #pragma unroll
  for (int i = 0; i < TPB_A; ++i){
    const int tok = tok_base + i;
    if (tok < ntok){
      const int a = __builtin_amdgcn_readfirstlane(asg[i]);   // block-uniform -> scalar branch
      float4 xa = *(const float4*)(x + (size_t)tok*DDIM + d0);
      float4 xb = *(const float4*)(x + (size_t)tok*DDIM + d1);
      #pragma unroll
      for (int k = 0; k < KC; ++k){
        if (a == k){
          acc0[k].x += xa.x; acc0[k].y += xa.y; acc0[k].z += xa.z; acc0[k].w += xa.w;
          acc1[k].x += xb.x; acc1[k].y += xb.y; acc1[k].z += xb.z; acc1[k].w += xb.w;
          cnt[k] += 1.f;
        }
      }
    }
  }
  unsigned short* dst = part + (size_t)blockIdx.x * (KC*DDIM);
  #pragma unroll
  for (int k = 0; k < KC; ++k){
    ushortv4 o0, o1;
    o0[0]=f2bf(acc0[k].x); o0[1]=f2bf(acc0[k].y); o0[2]=f2bf(acc0[k].z); o0[3]=f2bf(acc0[k].w);
    o1[0]=f2bf(acc1[k].x); o1[1]=f2bf(acc1[k].y); o1[2]=f2bf(acc1[k].z); o1[3]=f2bf(acc1[k].w);
    *(ushortv4*)(dst + k*DDIM + d0) = o0;
    *(ushortv4*)(dst + k*DDIM + d1) = o1;
  }
  if (t == 0){
    #pragma unroll
    for (int k = 0; k < KC; ++k) pcnts[blockIdx.x*KC + k] = cnt[k];
  }
}

// ---------------------------------------------------------------------------
// k_reduce1: nbA bf16 partials -> NCH fp32 chunk-partials (+ counts).
// grid = NCH * 8; block (ch,g) sums its 2048-element column stripe.
// ---------------------------------------------------------------------------
__global__ __launch_bounds__(256)
void k_reduce1(const unsigned short* __restrict__ part, const float* __restrict__ pcnts,
               float* __restrict__ stage2, float* __restrict__ cnt2, int nbA, int cs)
{
  const int ch = blockIdx.x >> 3;      // 0..NCH-1
  const int g  = blockIdx.x & 7;       // 0..7
  const int t  = threadIdx.x;
  const int col = g*2048 + t*8;        // element column, 8 wide
  const int b0 = ch*cs;

  float acc[8] = {0.f,0.f,0.f,0.f,0.f,0.f,0.f,0.f};
  for (int i = 0; i < cs; ++i){
    const int b = b0 + i;
    if (b < nbA){
      ushortv8 v = *(const ushortv8*)(part + (size_t)b*(KC*DDIM) + col);
      #pragma unroll
      for (int j = 0; j < 8; ++j) acc[j] += bf2f(v[j]);
    }
  }
  float4 o0 = make_float4(acc[0],acc[1],acc[2],acc[3]);
  float4 o1 = make_float4(acc[4],acc[5],acc[6],acc[7]);
  *(float4*)(stage2 + (size_t)ch*(KC*DDIM) + col)     = o0;
  *(float4*)(stage2 + (size_t)ch*(KC*DDIM) + col + 4) = o1;

  if (g == 0 && t < KC){
    float c = 0.f;
    for (int i = 0; i < cs; ++i){
      const int b = b0 + i;
      if (b < nbA) c += pcnts[b*KC + t];
    }
    cnt2[ch*KC + t] = c;
  }
}

// ---------------------------------------------------------------------------
// k_mid: chunk-partials -> centroid (count>0 else proto) -> normalize(1e-12)
// -> momentum -> normalize(1e-8) -> p2n bf16.  Block = cluster.
// ---------------------------------------------------------------------------
__global__ __launch_bounds__(256)
void k_mid(const float* __restrict__ stage2, const float* __restrict__ cnt2,
           const float* __restrict__ proto, unsigned short* __restrict__ p2nbf)
{
  const int k = blockIdx.x, t = threadIdx.x;
  const int wave = t >> 6, lane = t & 63;
  __shared__ float s1[4], s2[4];
  const int d0 = 4*t, d1 = 1024 + 4*t;

  float4 a = make_float4(0.f,0.f,0.f,0.f), b = make_float4(0.f,0.f,0.f,0.f);
  #pragma unroll
  for (int ch = 0; ch < NCH; ++ch){
    const float* p = stage2 + (size_t)ch*(KC*DDIM) + k*DDIM;
    float4 u = *(const float4*)(p + d0);
    float4 w = *(const float4*)(p + d1);
    a.x += u.x; a.y += u.y; a.z += u.z; a.w += u.w;
    b.x += w.x; b.y += w.y; b.z += w.z; b.w += w.w;
  }
  float c = 0.f;
  #pragma unroll
  for (int ch = 0; ch < NCH; ++ch) c += cnt2[ch*KC + k];

  float4 pr0 = *(const float4*)(proto + k*DDIM + d0);
  float4 pr1 = *(const float4*)(proto + k*DDIM + d1);

  float4 c0, c1;
  if (c > 0.f){
    const float inv = 1.0f / fmaxf(c, 1.0f);
    c0.x=a.x*inv; c0.y=a.y*inv; c0.z=a.z*inv; c0.w=a.w*inv;
    c1.x=b.x*inv; c1.y=b.y*inv; c1.z=b.z*inv; c1.w=b.w*inv;
  } else { c0 = pr0; c1 = pr1; }

  float ss = c0.x*c0.x + c0.y*c0.y + c0.z*c0.z + c0.w*c0.w
           + c1.x*c1.x + c1.y*c1.y + c1.z*c1.z + c1.w*c1.w;
  ss = wave_sum(ss);
  if (lane == 0) s1[wave] = ss;
  __syncthreads();
  ss = s1[0] + s1[1] + s1[2] + s1[3];
  const float invc = 1.0f / fmaxf(sqrtf(ss), 1e-12f);

  const float m = 0.999f, om = 1.0f - 0.999f;
  float4 p20, p21;
  p20.x = m*pr0.x + om*c0.x*invc; p20.y = m*pr0.y + om*c0.y*invc;
  p20.z = m*pr0.z + om*c0.z*invc; p20.w = m*pr0.w + om*c0.w*invc;
  p21.x = m*pr1.x + om*c1.x*invc; p21.y = m*pr1.y + om*c1.y*invc;
  p21.z = m*pr1.z + om*c1.z*invc; p21.w = m*pr1.w + om*c1.w*invc;

  float ss2 = p20.x*p20.x + p20.y*p20.y + p20.z*p20.z + p20.w*p20.w
            + p21.x*p21.x + p21.y*p21.y + p21.z*p21.z + p21.w*p21.w;
  ss2 = wave_sum(ss2);
  if (lane == 0) s2[wave] = ss2;
  __syncthreads();
  ss2 = s2[0] + s2[1] + s2[2] + s2[3];
  const float inv2 = 1.0f / fmaxf(sqrtf(ss2), 1e-8f);

  ushortv4 o0, o1;
  o0[0]=f2bf(p20.x*inv2); o0[1]=f2bf(p20.y*inv2); o0[2]=f2bf(p20.z*inv2); o0[3]=f2bf(p20.w*inv2);
  o1[0]=f2bf(p21.x*inv2); o1[1]=f2bf(p21.y*inv2); o1[2]=f2bf(p21.z*inv2); o1[3]=f2bf(p21.w*inv2);
  *(ushortv4*)(p2nbf + k*DDIM + d0) = o0;
  *(ushortv4*)(p2nbf + k*DDIM + d1) = o1;
}

// ---------------------------------------------------------------------------
// k_final: wave-per-token.  P2n bf16 in LDS; in-wave dot/norm reduce; scale
// computed by ALL lanes (no serial section, no loop barriers); gelu + nt store.
// ---------------------------------------------------------------------------
__global__ __launch_bounds__(256, 4)
void k_final(const float* __restrict__ x, const unsigned short* __restrict__ p2nbf,
             const float* __restrict__ plt, const float* __restrict__ plb,
             float* __restrict__ out, int ntok)
{
  __shared__ unsigned short Pl[KC*DDIM];   // 32 KB
  const int t = threadIdx.x;
  const int wave = t >> 6, lane = t & 63;

  #pragma unroll
  for (int j = 0; j < 8; ++j){
    const int e = (j*256 + t)*8;
    *(ushortv8*)(Pl + e) = *(const ushortv8*)(p2nbf + e);
  }
  __syncthreads();

  const float tau   = __expf(plt[0]);
  const float alpha = 1.0f / (1.0f + __expf(-plb[0]));

  const int tl0 = wave*4;
  const int tok_base = blockIdx.x * TPB_C;
  float4 X[8], N[8];
  {
    const int tok = tok_base + tl0;
    if (tok < ntok){
      #pragma unroll
      for (int j = 0; j < 8; ++j)
        X[j] = *(const float4*)(x + (size_t)tok*DDIM + j*256 + 4*lane);
    }
  }
  #pragma unroll
  for (int i = 0; i < 4; ++i){
    const int tok_i = tok_base + tl0 + i;
    const bool ldn = (i < 3) && (tok_i + 1 < ntok);
    if (ldn){
      #pragma unroll
      for (int j = 0; j < 8; ++j)
        N[j] = *(const float4*)(x + (size_t)(tok_i+1)*DDIM + j*256 + 4*lane);
    }
    if (tok_i < ntok){
      float ss = 0.f;
      #pragma unroll
      for (int j = 0; j < 8; ++j)
        ss += X[j].x*X[j].x + X[j].y*X[j].y + X[j].z*X[j].z + X[j].w*X[j].w;
      ss = wave_sum(ss);

      float v[KC];
      #pragma unroll
      for (int k = 0; k < KC; ++k){
        float s = 0.f;
        #pragma unroll
        for (int j = 0; j < 8; ++j){
          uint2 u = *(const uint2*)((const unsigned*)Pl + k*1024 + j*128 + 2*lane);
          s += X[j].x*bflo(u.x) + X[j].y*bfhi(u.x)
             + X[j].z*bflo(u.y) + X[j].w*bfhi(u.y);
        }
        v[k] = s;
      }
      float mx = butterfly8(v, lane);
      mx = fmaxf(mx, __shfl_xor(mx, 1, 64));
      mx = fmaxf(mx, __shfl_xor(mx, 2, 64));
      mx = fmaxf(mx, __shfl_xor(mx, 4, 64));   // every lane: max over 8 clusters

      const float inv  = 1.0f / fmaxf(sqrtf(ss), 1e-8f);
      const float s    = fminf(fmaxf(mx * inv, -1.0f), 1.0f);  // clip(max)==max(clip)
      const float dist = fminf(fmaxf(1.0f - s, 0.0f), 2.0f);
      const float nov  = 1.0f - __expf(-tau * dist);
      float sc = 1.0f - alpha + alpha * nov;
      sc = fminf(fmaxf(sc, 0.1f), 10.0f);

      float* o = out + (size_t)tok_i*DDIM;
      #pragma unroll
      for (int j = 0; j < 8; ++j){
        float4 g;
        g.x = gelu_tanh(X[j].x*sc); g.y = gelu_tanh(X[j].y*sc);
        g.z = gelu_tanh(X[j].z*sc); g.w = gelu_tanh(X[j].w*sc);
        nt_store4(g, o + j*256 + 4*lane);
      }
    }
    if (ldn){
      #pragma unroll
      for (int j = 0; j < 8; ++j) X[j] = N[j];
    }
  }
}

extern "C" void kernel_launch(void* const* d_in, const int* in_sizes, int n_in,
                              void* d_out, int out_size, void* d_ws, size_t ws_size,
                              hipStream_t stream)
{
  const float* x         = (const float*)d_in[0];
  const float* proto     = (const float*)d_in[1];
  const float* log_tau   = (const float*)d_in[2];
  const float* log_blend = (const float*)d_in[3];
  float* out = (float*)d_out;
  float* ws  = (float*)d_ws;

  const int ntok = in_sizes[0] / DDIM;   // 16384 (element count / D)

  // ws layout (float units)
  unsigned short* pbf    = (unsigned short*)(ws);            // 16384 bf16 = 8192 f
  unsigned short* p2nbf  = (unsigned short*)(ws + 8192);     // 16384 bf16
  float*          pcnts  = ws + 16384;                       // nbA*8 (<= 8192)
  float*          cnt2   = ws + 24576;                       // NCH*8 = 256
  float*          stage2 = ws + 24832;                       // NCH*16384 = 524288
  unsigned short* part   = (unsigned short*)(ws + 549120);   // nbA*16384 bf16

  const int nbA = (ntok + TPB_A - 1) / TPB_A;    // 1024
  const int nbC = (ntok + TPB_C - 1) / TPB_C;    // 1024
  const int cs  = (nbA + NCH - 1) / NCH;         // 32

  k_pre    <<<KC,     256, 0, stream>>>(proto, pbf);
  k_assign <<<nbA,    256, 0, stream>>>(x, pbf, part, pcnts, ntok);
  k_reduce1<<<NCH*8,  256, 0, stream>>>(part, pcnts, stage2, cnt2, nbA, cs);
  k_mid    <<<KC,     256, 0, stream>>>(stage2, cnt2, proto, p2nbf);
  k_final  <<<nbC,    256, 0, stream>>>(x, p2nbf, log_tau, log_blend, out, ntok);
}